// Round 3
// baseline (495.521 us; speedup 1.0000x reference)
//
#include <hip/hip_runtime.h>
#include <cstdint>
#include <cstddef>

typedef __bf16 bf16;
typedef __bf16 bf16x8 __attribute__((ext_vector_type(8)));
typedef __bf16 bf16v4 __attribute__((ext_vector_type(4)));
typedef float  f32x4  __attribute__((ext_vector_type(4)));

// Problem constants: B=128, N=49, G=4096, H=1024, A=1024
#define PB   128
#define PN   49
#define PG   4096
#define PH   1024
#define PA   1024
#define PM1  (PB * PN)   // 6272

// ---------------------------------------------------------------------------
// dtype detect: flag=1 -> bf16 inputs, 0 -> fp32.
// ---------------------------------------------------------------------------
__global__ __launch_bounds__(256) void detect_kernel(
    const unsigned short* __restrict__ raw, int* __restrict__ flag)
{
    __shared__ int cnt;
    if (threadIdx.x == 0) cnt = 0;
    __syncthreads();
    unsigned short u = raw[threadIdx.x];
    float x = __uint_as_float(((unsigned int)u) << 16);
    float a = fabsf(x);
    atomicAdd(&cnt, (a >= 1e-7f && a <= 128.f) ? 1 : 0);
    __syncthreads();
    if (threadIdx.x == 0) flag[0] = (cnt >= 200) ? 1 : 0;
}

__device__ __forceinline__ float ldin(const void* p, size_t i, bool in32) {
    return in32 ? ((const float*)p)[i] : (float)((const bf16*)p)[i];
}

// load 8 consecutive elems of x (fp32 or bf16) as float
__device__ __forceinline__ void ldx8(const void* x, size_t k0, bool in32, float* xv) {
    if (in32) {
        f32x4 lo = *(const f32x4*)((const float*)x + k0);
        f32x4 hi = *(const f32x4*)((const float*)x + k0 + 4);
#pragma unroll
        for (int j = 0; j < 4; ++j) { xv[j] = lo[j]; xv[4 + j] = hi[j]; }
    } else {
        bf16x8 v = *(const bf16x8*)((const bf16*)x + k0);
#pragma unroll
        for (int j = 0; j < 8; ++j) xv[j] = (float)v[j];
    }
}

// raw (flag dtype) -> bf16, 8 elems/thread, grid-stride (guide G11)
__global__ __launch_bounds__(256) void cvt_kernel(
    const void* __restrict__ in, const int* __restrict__ flag,
    bf16* __restrict__ out, size_t total)
{
    const bool in32 = (flag[0] == 0);
    const size_t stride = (size_t)gridDim.x * 256 * 8;
    for (size_t i = ((size_t)blockIdx.x * 256 + threadIdx.x) * 8; i < total; i += stride) {
        bf16x8 o;
        if (in32) {
            f32x4 lo = *(const f32x4*)((const float*)in + i);
            f32x4 hi = *(const f32x4*)((const float*)in + i + 4);
#pragma unroll
            for (int j = 0; j < 4; ++j) { o[j] = (bf16)lo[j]; o[4 + j] = (bf16)hi[j]; }
        } else {
            o = *(const bf16x8*)((const bf16*)in + i);
        }
        *(bf16x8*)(out + i) = o;
    }
}

// ---------------------------------------------------------------------------
// GEMM: C[M,N] = A[M,K] @ Bt^T.  128x128 tile, BK=64, 4 waves,
// mfma 16x16x32 bf16.  bf16 operands staged via global_load_lds(16B) async
// DMA with a (chunk+row)&7 rotation on the SOURCE address so frag
// ds_read_b128 spreads over all 8 bank groups (0 conflicts, verified).
// AADAPT=1: A is a raw input (dtype per flag), staged through VGPRs.
// Bijective XCD-aware block swizzle (m204) for L2 panel reuse.
// Split-K via bz plane (fp32 Cf or bf16 Cb per BF16OUT).
// ---------------------------------------------------------------------------
template <int BF16OUT, int AADAPT>
__global__ __launch_bounds__(256, 2) void gemm_kernel(
    const void* __restrict__ Araw, const bf16* __restrict__ Bt0,
    const int* __restrict__ flag,
    float* __restrict__ Cf, bf16* __restrict__ Cb,
    int M, int N, int K, int kTilesPerSplit)
{
    __shared__ __align__(16) bf16 lds[2 * 128 * 64];
    bf16* As  = lds;
    bf16* Bs0 = lds + 128 * 64;

    const bool a32 = AADAPT && (flag[0] == 0);

    // ---- bijective XCD swizzle of the flattened block id ----
    const int gx = gridDim.x, gy = gridDim.y;
    const int nwg = gx * gy * (int)gridDim.z;
    int flat = blockIdx.x + gx * (blockIdx.y + gy * blockIdx.z);
    {
        const int q8 = nwg >> 3, r8 = nwg & 7;
        const int xcd = flat & 7, sub = flat >> 3;
        flat = (xcd < r8 ? xcd * (q8 + 1) : r8 * (q8 + 1) + (xcd - r8) * q8) + sub;
    }
    const int bx  = flat % gx;
    const int byz = flat / gx;
    const int by  = byz % gy;
    const int bz  = byz / gy;

    const int tid  = threadIdx.x;
    const int m0   = by * 128;
    const int n0   = bx * 128;
    const int kt0  = bz * kTilesPerSplit;

    const int wave = tid >> 6;
    const int lane = tid & 63;
    const int wm   = (wave >> 1) * 64;
    const int wn   = (wave & 1) * 64;
    const int lm   = lane & 15;
    const int q    = lane >> 4;

    f32x4 acc[4][4];
#pragma unroll
    for (int i = 0; i < 4; ++i)
#pragma unroll
        for (int j = 0; j < 4; ++j) acc[i][j] = (f32x4)0.0f;

    for (int kt = 0; kt < kTilesPerSplit; ++kt) {
        const int k0 = (kt0 + kt) * 64;
#pragma unroll
        for (int it = 0; it < 4; ++it) {
            int p   = it * 256 + tid;
            int row = p >> 3;
            int lc  = ((p & 7) - row) & 7;       // logical chunk held by phys slot p
            size_t offB = (size_t)(n0 + row) * K + k0 + lc * 8;
            __builtin_amdgcn_global_load_lds((void*)(Bt0 + offB), (void*)(Bs0 + p * 8), 16, 0, 0);
            size_t offA = (size_t)(m0 + row) * K + k0 + lc * 8;
            if (AADAPT) {
                bf16x8 va;
                if (a32) {
                    const float* pf = (const float*)Araw + offA;
                    f32x4 lo = *(const f32x4*)pf, hi = *(const f32x4*)(pf + 4);
#pragma unroll
                    for (int j = 0; j < 4; ++j) { va[j] = (bf16)lo[j]; va[4 + j] = (bf16)hi[j]; }
                } else {
                    va = *(const bf16x8*)((const bf16*)Araw + offA);
                }
                *(bf16x8*)(As + p * 8) = va;
            } else {
                __builtin_amdgcn_global_load_lds((void*)((const bf16*)Araw + offA),
                                                 (void*)(As + p * 8), 16, 0, 0);
            }
        }
        __syncthreads();

#pragma unroll
        for (int s = 0; s < 2; ++s) {
            bf16x8 af[4], bf0[4];
            const int c = s * 4 + q;
#pragma unroll
            for (int mi = 0; mi < 4; ++mi) {
                int row  = wm + mi * 16 + lm;
                int slot = row * 8 + ((c + row) & 7);
                af[mi] = *(const bf16x8*)(As + slot * 8);
            }
#pragma unroll
            for (int ni = 0; ni < 4; ++ni) {
                int row  = wn + ni * 16 + lm;
                int slot = row * 8 + ((c + row) & 7);
                bf0[ni] = *(const bf16x8*)(Bs0 + slot * 8);
            }
#pragma unroll
            for (int mi = 0; mi < 4; ++mi)
#pragma unroll
                for (int ni = 0; ni < 4; ++ni)
                    acc[mi][ni] = __builtin_amdgcn_mfma_f32_16x16x32_bf16(
                        af[mi], bf0[ni], acc[mi][ni], 0, 0, 0);
        }
        __syncthreads();
    }

#pragma unroll
    for (int mi = 0; mi < 4; ++mi)
#pragma unroll
        for (int ni = 0; ni < 4; ++ni)
#pragma unroll
            for (int r = 0; r < 4; ++r) {
                int row = m0 + wm + mi * 16 + q * 4 + r;
                int col = n0 + wn + ni * 16 + lm;
                if (BF16OUT)
                    Cb[(size_t)bz * M * N + (size_t)row * N + col] = (bf16)acc[mi][ni][r];
                else
                    Cf[(size_t)bz * M * N + (size_t)row * N + col] = acc[mi][ni][r];
            }
}

// ---------------------------------------------------------------------------
// Transpose [R,C]->[C,R] bf16 out from raw input (dtype per flag).
// grid (C/64, R/64).
// ---------------------------------------------------------------------------
__global__ __launch_bounds__(256) void transpose_kernel(
    const void* __restrict__ in, const int* __restrict__ flag,
    bf16* __restrict__ out, int R, int C)
{
    __shared__ bf16 tile[64][65];
    const bool in32 = (flag[0] == 0);
    const int r0 = blockIdx.y * 64, c0 = blockIdx.x * 64;
    const int tx = threadIdx.x & 15, ty = threadIdx.x >> 4;
#pragma unroll
    for (int it = 0; it < 4; ++it) {
        int r = it * 16 + ty;
        size_t base = (size_t)(r0 + r) * C + c0 + tx * 4;
        if (in32) {
            f32x4 v = *(const f32x4*)((const float*)in + base);
#pragma unroll
            for (int i = 0; i < 4; ++i) tile[r][tx * 4 + i] = (bf16)v[i];
        } else {
            bf16v4 v = *(const bf16v4*)((const bf16*)in + base);
#pragma unroll
            for (int i = 0; i < 4; ++i) tile[r][tx * 4 + i] = v[i];
        }
    }
    __syncthreads();
#pragma unroll
    for (int it = 0; it < 4; ++it) {
        int c = it * 16 + ty;
        bf16v4 v;
#pragma unroll
        for (int i = 0; i < 4; ++i) v[i] = tile[tx * 4 + i][c];
        *(bf16v4*)(out + (size_t)(c0 + c) * R + r0 + tx * 4) = v;
    }
}

// ---------------------------------------------------------------------------
// Fused split-K reduce (PLANES bf16 planes) + transpose.
// in: PLANES bf16 planes [R,C]; outT[C,R] = (sum planes)^T.  grid (C/64,R/64).
// ---------------------------------------------------------------------------
template <int PLANES>
__global__ __launch_bounds__(256) void transpose_red_kernel(
    const bf16* __restrict__ in, bf16* __restrict__ outT, int R, int C)
{
    __shared__ bf16 tile[64][65];
    const size_t plane = (size_t)R * C;
    const int r0 = blockIdx.y * 64, c0 = blockIdx.x * 64;
    const int tx = threadIdx.x & 15, ty = threadIdx.x >> 4;
#pragma unroll
    for (int it = 0; it < 4; ++it) {
        int r = it * 16 + ty;
        size_t base = (size_t)(r0 + r) * C + c0 + tx * 4;
        float s[4] = {0.f, 0.f, 0.f, 0.f};
#pragma unroll
        for (int p = 0; p < PLANES; ++p) {
            bf16v4 v = *(const bf16v4*)(in + p * plane + base);
#pragma unroll
            for (int i = 0; i < 4; ++i) s[i] += (float)v[i];
        }
#pragma unroll
        for (int i = 0; i < 4; ++i) tile[r][tx * 4 + i] = (bf16)s[i];
    }
    __syncthreads();
#pragma unroll
    for (int it = 0; it < 4; ++it) {
        int c = it * 16 + ty;
        bf16v4 v;
#pragma unroll
        for (int i = 0; i < 4; ++i) v[i] = tile[tx * 4 + i][c];
        *(bf16v4*)(outT + (size_t)(c0 + c) * R + r0 + tx * 4) = v;
    }
}

// elementwise reduce of 4 bf16 planes -> single bf16, 8 elems/thread
__global__ __launch_bounds__(256) void reduce4_kernel(
    const bf16* __restrict__ in, bf16* __restrict__ out, size_t n)
{
    size_t i = ((size_t)blockIdx.x * 256 + threadIdx.x) * 8;
    float s[8] = {0,0,0,0,0,0,0,0};
#pragma unroll
    for (int p = 0; p < 4; ++p) {
        bf16x8 v = *(const bf16x8*)(in + (size_t)p * n + i);
#pragma unroll
        for (int j = 0; j < 8; ++j) s[j] += (float)v[j];
    }
    bf16x8 o;
#pragma unroll
    for (int j = 0; j < 8; ++j) o[j] = (bf16)s[j];
    *(bf16x8*)(out + i) = o;
}

// ---------------------------------------------------------------------------
// rowdot: y[c] = sum_k x[k] * Wt[c,k] (+ addv[c]).  One WAVE per output
// element, bf16x8 vector loads, shfl tree reduce.  grid (C/4), block 256.
// ---------------------------------------------------------------------------
__global__ __launch_bounds__(256) void rowdot_kernel(
    const void* __restrict__ x, const bf16* __restrict__ Wt,
    const void* __restrict__ addv, const int* __restrict__ flag, int xMode,
    float* __restrict__ y, int K)
{
    const bool raw32 = (flag[0] == 0);
    const bool x32   = (xMode == 0) || raw32;
    const int wave = threadIdx.x >> 6, lane = threadIdx.x & 63;
    const int c = blockIdx.x * 4 + wave;
    float s = 0.f;
    for (int k0 = lane * 8; k0 < K; k0 += 512) {
        bf16x8 w = *(const bf16x8*)(Wt + (size_t)c * K + k0);
        float xv[8];
        ldx8(x, (size_t)k0, x32, xv);
#pragma unroll
        for (int j = 0; j < 8; ++j) s += xv[j] * (float)w[j];
    }
#pragma unroll
    for (int off = 32; off; off >>= 1) s += __shfl_down(s, off);
    if (lane == 0) {
        float a = addv ? ldin(addv, c, raw32) : 0.f;
        y[c] = s + a;
    }
}

// score[b,n] = v . tanh(sum_2 t2P + sum_4 sprojP + tbias + cov*Wc); grid (PN,PB)
__global__ __launch_bounds__(256) void scores_kernel(
    const bf16* __restrict__ tP, const float* __restrict__ sprojP,
    const float* __restrict__ tbias, const void* __restrict__ cov,
    const void* __restrict__ Wc, const void* __restrict__ v,
    const int* __restrict__ flag, float* __restrict__ sc)
{
    const bool in32 = (flag[0] == 0);
    const int n = blockIdx.x, b = blockIdx.y, tid = threadIdx.x;
    __shared__ float red[4];
    const size_t trow = (size_t)(b * PN + n) * PA;
    const float cv = ldin(cov, b * PN + n, in32);
    float s = 0.f;
#pragma unroll
    for (int i = 0; i < 4; ++i) {
        int a = tid + i * 256;
        float tv = 0.f;
#pragma unroll
        for (int p = 0; p < 2; ++p)
            tv += (float)tP[(size_t)p * ((size_t)PM1 * PA) + trow + a];
        float sp = 0.f;
#pragma unroll
        for (int p = 0; p < 4; ++p)
            sp += sprojP[(size_t)p * (PB * PA) + (size_t)b * PA + a];
        s += ldin(v, a, in32) * tanhf(tv + sp + tbias[a] + cv * ldin(Wc, a, in32));
    }
#pragma unroll
    for (int off = 32; off; off >>= 1) s += __shfl_down(s, off);
    if ((tid & 63) == 0) red[tid >> 6] = s;
    __syncthreads();
    if (tid == 0) sc[b * PN + n] = red[0] + red[1] + red[2] + red[3];
}

// out[b,h] = cbias[h] + sum_n softmax(sc[b,:])_n * gstar[b*PN+n, h]
// (sum alpha = 1 so the +cbias of g_star folds to a single add).
// grid (PB), block 256, 4 h/thread.  Output dtype per flag.
__global__ __launch_bounds__(256) void context_kernel(
    const float* __restrict__ sc, const bf16* __restrict__ gstar,
    const float* __restrict__ cbias, const int* __restrict__ flag,
    void* __restrict__ out)
{
    const int b = blockIdx.x, tid = threadIdx.x;
    const int h = tid * 4;
    float e[PN];
    float mx = -1e30f;
    for (int n = 0; n < PN; ++n) mx = fmaxf(mx, sc[b * PN + n]);
    float sum = 0.f;
    for (int n = 0; n < PN; ++n) { e[n] = expf(sc[b * PN + n] - mx); sum += e[n]; }
    const float inv = 1.f / sum;
    f32x4 cb = *(const f32x4*)(cbias + h);
    float acc[4] = {cb[0], cb[1], cb[2], cb[3]};
    for (int n = 0; n < PN; ++n) {
        float al = e[n] * inv;
        bf16v4 g = *(const bf16v4*)(gstar + (size_t)(b * PN + n) * PH + h);
#pragma unroll
        for (int j = 0; j < 4; ++j) acc[j] += al * (float)g[j];
    }
    if (flag[0]) {
        bf16v4 o;
#pragma unroll
        for (int j = 0; j < 4; ++j) o[j] = (bf16)acc[j];
        *(bf16v4*)((bf16*)out + (size_t)b * PH + h) = o;
    } else {
        f32x4 o;
#pragma unroll
        for (int j = 0; j < 4; ++j) o[j] = acc[j];
        *(f32x4*)((float*)out + (size_t)b * PH + h) = o;
    }
}

// ---------------------------------------------------------------------------
extern "C" void kernel_launch(void* const* d_in, const int* in_sizes, int n_in,
                              void* d_out, int out_size, void* d_ws, size_t ws_size,
                              hipStream_t stream)
{
    const void* GF  = d_in[0];
    const void* s_t = d_in[1];
    const void* cov = d_in[2];
    const void* Wg  = d_in[3];
    const void* bg  = d_in[4];
    const void* Wgs = d_in[5];
    const void* bgs = d_in[6];
    const void* Wh  = d_in[7];
    const void* Ws  = d_in[8];
    const void* Wc  = d_in[9];
    const void* v   = d_in[10];
    (void)in_sizes; (void)n_in; (void)out_size; (void)ws_size;

    // ---- workspace plan (peak 116 MiB; lifetime-overlap) ----
    // S1 cvt/transpose  S2 biases  S3 Wggs  S5 g_star  S5b red4  S5c t2
    // S6 sproj  S7 scores  S8 context
    const size_t MB = 1u << 20;
    char* W = (char*)d_ws;
    bf16*  GFb    = (bf16*) (W + 0);               // 49 MiB   [S1-S5]
    bf16*  g_star = (bf16*) (W + 0);               // 12.25MiB [S5b-S8], over dead GFb
    int*   flag   = (int*)  (W + 52 * MB);
    float* tbias  = (float*)(W + 52 * MB + 4096);
    float* cbias  = (float*)(W + 52 * MB + 8192);
    float* sc     = (float*)(W + 52 * MB + 12288); // 25 KB
    bf16*  s_tb   = (bf16*) (W + 52 * MB + 262144);// 0.25 MiB
    bf16*  WsT    = (bf16*) (W + 53 * MB);         // 2 MiB    [S1-S6]
    bf16*  WhT    = (bf16*) (W + 55 * MB);         // 2 MiB    [S1-S5c]
    float* sprojP = (float*)(W + 57 * MB);         // 2 MiB (4 planes) [S6-S7]
    bf16*  WgsT   = (bf16*) (W + 59 * MB);         // 8 MiB    [S1-S3]
    bf16*  WggsT  = (bf16*) (W + 59 * MB);         // 8 MiB    [S3b-S5], over dead WgsT
    bf16*  WggsS  = (bf16*) (W + 67 * MB);         // 32 MiB (4 planes) [S3-S3b]
    bf16*  gP     = (bf16*) (W + 67 * MB);         // 49 MiB (4 planes) [S5-S5b]
    bf16*  t2P    = (bf16*) (W + 67 * MB);         // 24.5 MiB (2 planes) [S5c-S7]

    dim3 blk(256);

    // 0. dtype detect
    detect_kernel<<<dim3(1), blk, 0, stream>>>((const unsigned short*)GF, flag);

    // 1. conversions / transposes of inputs (no Wg conversion: the Wggs GEMM
    //    reads raw Wg via the AADAPT reg-staging path)
    cvt_kernel<<<dim3(2048), blk, 0, stream>>>(GF, flag, GFb, (size_t)PM1 * PG);
    cvt_kernel<<<dim3(64), blk, 0, stream>>>(s_t, flag, s_tb, (size_t)PB * PH);
    transpose_kernel<<<dim3(PH / 64, PG / 64), blk, 0, stream>>>(Wgs, flag, WgsT, PG, PH);
    transpose_kernel<<<dim3(PA / 64, PH / 64), blk, 0, stream>>>(Wh, flag, WhT, PH, PA);
    transpose_kernel<<<dim3(PA / 64, PH / 64), blk, 0, stream>>>(Ws, flag, WsT, PH, PA);

    // 2. cbias = bg@Wgs + bgs;  tbias = cbias@Wh
    rowdot_kernel<<<dim3(PH / 4), blk, 0, stream>>>(bg, WgsT, bgs, flag, 1, cbias, PG);
    rowdot_kernel<<<dim3(PA / 4), blk, 0, stream>>>(cbias, WhT, nullptr, flag, 0, tbias, PH);

    // 3. Wggs[G,H] = Wg @ Wgs  (AADAPT raw-A, split-K 4 -> 1024 blocks)
    //    fused reduce+transpose -> WggsT [H,G]
    gemm_kernel<1, 1><<<dim3(PH / 128, PG / 128, 4), blk, 0, stream>>>(
        Wg, WgsT, flag, nullptr, WggsS, PG, PH, PG, (PG / 64) / 4);
    transpose_red_kernel<4><<<dim3(PH / 64, PG / 64), blk, 0, stream>>>(
        WggsS, WggsT, PG, PH);

    // 5. g_star planes = GF @ Wggs  (split-K 4 -> 1568 blocks), then reduce
    gemm_kernel<1, 0><<<dim3(PH / 128, PM1 / 128, 4), blk, 0, stream>>>(
        GFb, WggsT, flag, nullptr, gP, PM1, PH, PG, (PG / 64) / 4);
    reduce4_kernel<<<dim3((PM1 * PH) / 2048), blk, 0, stream>>>(
        gP, g_star, (size_t)PM1 * PH);

    // 5c. t2 = g_star @ Wh  (split-K 2 -> 784 blocks, bf16 planes)
    gemm_kernel<1, 0><<<dim3(PA / 128, PM1 / 128, 2), blk, 0, stream>>>(
        g_star, WhT, flag, nullptr, t2P, PM1, PA, PH, (PH / 64) / 2);

    // 6. sproj = s_t @ Ws   (split-K 4, fp32 planes)
    gemm_kernel<0, 0><<<dim3(PA / 128, 1, 4), blk, 0, stream>>>(
        s_tb, WsT, flag, sprojP, nullptr, PB, PA, PH, (PH / 64) / 4);

    // 7. scores (adds tbias so t2 needs no bias)
    scores_kernel<<<dim3(PN, PB), blk, 0, stream>>>(
        t2P, sprojP, tbias, cov, Wc, v, flag, sc);

    // 8. context: softmax + weighted sum of g_star + cbias -> out
    context_kernel<<<dim3(PB), blk, 0, stream>>>(sc, g_star, cbias, flag, d_out);
}

// Round 4
// 434.045 us; speedup vs baseline: 1.1416x; 1.1416x over previous
//
#include <hip/hip_runtime.h>
#include <cstdint>
#include <cstddef>

typedef __bf16 bf16;
typedef __bf16 bf16x8 __attribute__((ext_vector_type(8)));
typedef __bf16 bf16v4 __attribute__((ext_vector_type(4)));
typedef float  f32x4  __attribute__((ext_vector_type(4)));

// Problem constants: B=128, N=49, G=4096, H=1024, A=1024
#define PB   128
#define PN   49
#define PG   4096
#define PH   1024
#define PA   1024
#define PM1  (PB * PN)   // 6272

// ---------------------------------------------------------------------------
// dtype detect: flag=1 -> bf16 inputs, 0 -> fp32.
// ---------------------------------------------------------------------------
__global__ __launch_bounds__(256) void detect_kernel(
    const unsigned short* __restrict__ raw, int* __restrict__ flag)
{
    __shared__ int cnt;
    if (threadIdx.x == 0) cnt = 0;
    __syncthreads();
    unsigned short u = raw[threadIdx.x];
    float x = __uint_as_float(((unsigned int)u) << 16);
    float a = fabsf(x);
    atomicAdd(&cnt, (a >= 1e-7f && a <= 128.f) ? 1 : 0);
    __syncthreads();
    if (threadIdx.x == 0) flag[0] = (cnt >= 200) ? 1 : 0;
}

__device__ __forceinline__ float ldin(const void* p, size_t i, bool in32) {
    return in32 ? ((const float*)p)[i] : (float)((const bf16*)p)[i];
}

// load 8 consecutive elems of x (fp32 or bf16) as float
__device__ __forceinline__ void ldx8(const void* x, size_t k0, bool in32, float* xv) {
    if (in32) {
        f32x4 lo = *(const f32x4*)((const float*)x + k0);
        f32x4 hi = *(const f32x4*)((const float*)x + k0 + 4);
#pragma unroll
        for (int j = 0; j < 4; ++j) { xv[j] = lo[j]; xv[4 + j] = hi[j]; }
    } else {
        bf16x8 v = *(const bf16x8*)((const bf16*)x + k0);
#pragma unroll
        for (int j = 0; j < 8; ++j) xv[j] = (float)v[j];
    }
}

// raw (flag dtype) -> bf16, 8 elems/thread, grid-stride
__global__ __launch_bounds__(256) void cvt_kernel(
    const void* __restrict__ in, const int* __restrict__ flag,
    bf16* __restrict__ out, size_t total)
{
    const bool in32 = (flag[0] == 0);
    const size_t stride = (size_t)gridDim.x * 256 * 8;
    for (size_t i = ((size_t)blockIdx.x * 256 + threadIdx.x) * 8; i < total; i += stride) {
        bf16x8 o;
        if (in32) {
            f32x4 lo = *(const f32x4*)((const float*)in + i);
            f32x4 hi = *(const f32x4*)((const float*)in + i + 4);
#pragma unroll
            for (int j = 0; j < 4; ++j) { o[j] = (bf16)lo[j]; o[4 + j] = (bf16)hi[j]; }
        } else {
            o = *(const bf16x8*)((const bf16*)in + i);
        }
        *(bf16x8*)(out + i) = o;
    }
}

// ---------------------------------------------------------------------------
// GEMM: C[M,N] = A[M,K] @ Bt^T.  128x128 tile, BK=64, 4 waves,
// mfma 16x16x32 bf16.  Both operands bf16, staged via global_load_lds(16B)
// async DMA (dest = wave-uniform base + lane*16) with a (chunk+row)&7
// rotation applied on the SOURCE address so frag ds_read_b128 spreads over
// all 8 bank groups (0 conflicts, rocprof-verified).
// NOTE: the AADAPT reg-staging variant was removed — measured 141 us vs
// ~55 us DMA+cvt for the same GEMM (R3 post-mortem): reg-staging serializes
// load->vmcnt->cvt->ds_write on the critical path each K-step.
// Bijective XCD-aware block swizzle (m204) for L2 panel reuse.
// Split-K via bz plane (fp32 Cf or bf16 Cb per BF16OUT).
// ---------------------------------------------------------------------------
template <int BF16OUT>
__global__ __launch_bounds__(256, 2) void gemm_kernel(
    const bf16* __restrict__ A, const bf16* __restrict__ Bt0,
    float* __restrict__ Cf, bf16* __restrict__ Cb,
    int M, int N, int K, int kTilesPerSplit)
{
    __shared__ __align__(16) bf16 lds[2 * 128 * 64];
    bf16* As  = lds;
    bf16* Bs0 = lds + 128 * 64;

    // ---- bijective XCD swizzle of the flattened block id ----
    const int gx = gridDim.x, gy = gridDim.y;
    const int nwg = gx * gy * (int)gridDim.z;
    int flat = blockIdx.x + gx * (blockIdx.y + gy * blockIdx.z);
    {
        const int q8 = nwg >> 3, r8 = nwg & 7;
        const int xcd = flat & 7, sub = flat >> 3;
        flat = (xcd < r8 ? xcd * (q8 + 1) : r8 * (q8 + 1) + (xcd - r8) * q8) + sub;
    }
    const int bx  = flat % gx;
    const int byz = flat / gx;
    const int by  = byz % gy;
    const int bz  = byz / gy;

    const int tid  = threadIdx.x;
    const int m0   = by * 128;
    const int n0   = bx * 128;
    const int kt0  = bz * kTilesPerSplit;

    const int wave = tid >> 6;
    const int lane = tid & 63;
    const int wm   = (wave >> 1) * 64;
    const int wn   = (wave & 1) * 64;
    const int lm   = lane & 15;
    const int q    = lane >> 4;

    f32x4 acc[4][4];
#pragma unroll
    for (int i = 0; i < 4; ++i)
#pragma unroll
        for (int j = 0; j < 4; ++j) acc[i][j] = (f32x4)0.0f;

    for (int kt = 0; kt < kTilesPerSplit; ++kt) {
        const int k0 = (kt0 + kt) * 64;
#pragma unroll
        for (int it = 0; it < 4; ++it) {
            int p   = it * 256 + tid;
            int row = p >> 3;
            int lc  = ((p & 7) - row) & 7;       // logical chunk held by phys slot p
            size_t offB = (size_t)(n0 + row) * K + k0 + lc * 8;
            __builtin_amdgcn_global_load_lds((void*)(Bt0 + offB), (void*)(Bs0 + p * 8), 16, 0, 0);
            size_t offA = (size_t)(m0 + row) * K + k0 + lc * 8;
            __builtin_amdgcn_global_load_lds((void*)(A + offA), (void*)(As + p * 8), 16, 0, 0);
        }
        __syncthreads();

#pragma unroll
        for (int s = 0; s < 2; ++s) {
            bf16x8 af[4], bf0[4];
            const int c = s * 4 + q;
#pragma unroll
            for (int mi = 0; mi < 4; ++mi) {
                int row  = wm + mi * 16 + lm;
                int slot = row * 8 + ((c + row) & 7);
                af[mi] = *(const bf16x8*)(As + slot * 8);
            }
#pragma unroll
            for (int ni = 0; ni < 4; ++ni) {
                int row  = wn + ni * 16 + lm;
                int slot = row * 8 + ((c + row) & 7);
                bf0[ni] = *(const bf16x8*)(Bs0 + slot * 8);
            }
#pragma unroll
            for (int mi = 0; mi < 4; ++mi)
#pragma unroll
                for (int ni = 0; ni < 4; ++ni)
                    acc[mi][ni] = __builtin_amdgcn_mfma_f32_16x16x32_bf16(
                        af[mi], bf0[ni], acc[mi][ni], 0, 0, 0);
        }
        __syncthreads();
    }

#pragma unroll
    for (int mi = 0; mi < 4; ++mi)
#pragma unroll
        for (int ni = 0; ni < 4; ++ni)
#pragma unroll
            for (int r = 0; r < 4; ++r) {
                int row = m0 + wm + mi * 16 + q * 4 + r;
                int col = n0 + wn + ni * 16 + lm;
                if (BF16OUT)
                    Cb[(size_t)bz * M * N + (size_t)row * N + col] = (bf16)acc[mi][ni][r];
                else
                    Cf[(size_t)bz * M * N + (size_t)row * N + col] = acc[mi][ni][r];
            }
}

// ---------------------------------------------------------------------------
// Transpose [R,C]->[C,R] bf16 out from raw input (dtype per flag).
// grid (C/64, R/64).
// ---------------------------------------------------------------------------
__global__ __launch_bounds__(256) void transpose_kernel(
    const void* __restrict__ in, const int* __restrict__ flag,
    bf16* __restrict__ out, int R, int C)
{
    __shared__ bf16 tile[64][65];
    const bool in32 = (flag[0] == 0);
    const int r0 = blockIdx.y * 64, c0 = blockIdx.x * 64;
    const int tx = threadIdx.x & 15, ty = threadIdx.x >> 4;
#pragma unroll
    for (int it = 0; it < 4; ++it) {
        int r = it * 16 + ty;
        size_t base = (size_t)(r0 + r) * C + c0 + tx * 4;
        if (in32) {
            f32x4 v = *(const f32x4*)((const float*)in + base);
#pragma unroll
            for (int i = 0; i < 4; ++i) tile[r][tx * 4 + i] = (bf16)v[i];
        } else {
            bf16v4 v = *(const bf16v4*)((const bf16*)in + base);
#pragma unroll
            for (int i = 0; i < 4; ++i) tile[r][tx * 4 + i] = v[i];
        }
    }
    __syncthreads();
#pragma unroll
    for (int it = 0; it < 4; ++it) {
        int c = it * 16 + ty;
        bf16v4 v;
#pragma unroll
        for (int i = 0; i < 4; ++i) v[i] = tile[tx * 4 + i][c];
        *(bf16v4*)(out + (size_t)(c0 + c) * R + r0 + tx * 4) = v;
    }
}

// elementwise reduce of 4 bf16 planes -> single bf16, 8 elems/thread
__global__ __launch_bounds__(256) void reduce4_kernel(
    const bf16* __restrict__ in, bf16* __restrict__ out, size_t n)
{
    size_t i = ((size_t)blockIdx.x * 256 + threadIdx.x) * 8;
    float s[8] = {0,0,0,0,0,0,0,0};
#pragma unroll
    for (int p = 0; p < 4; ++p) {
        bf16x8 v = *(const bf16x8*)(in + (size_t)p * n + i);
#pragma unroll
        for (int j = 0; j < 8; ++j) s[j] += (float)v[j];
    }
    bf16x8 o;
#pragma unroll
    for (int j = 0; j < 8; ++j) o[j] = (bf16)s[j];
    *(bf16x8*)(out + i) = o;
}

// ---------------------------------------------------------------------------
// rowdot: y[c] = sum_k x[k] * Wt[c,k] (+ addv[c]).  One WAVE per output
// element, bf16x8 vector loads, shfl tree reduce.  grid (C/4), block 256.
// ---------------------------------------------------------------------------
__global__ __launch_bounds__(256) void rowdot_kernel(
    const void* __restrict__ x, const bf16* __restrict__ Wt,
    const void* __restrict__ addv, const int* __restrict__ flag, int xMode,
    float* __restrict__ y, int K)
{
    const bool raw32 = (flag[0] == 0);
    const bool x32   = (xMode == 0) || raw32;
    const int wave = threadIdx.x >> 6, lane = threadIdx.x & 63;
    const int c = blockIdx.x * 4 + wave;
    float s = 0.f;
    for (int k0 = lane * 8; k0 < K; k0 += 512) {
        bf16x8 w = *(const bf16x8*)(Wt + (size_t)c * K + k0);
        float xv[8];
        ldx8(x, (size_t)k0, x32, xv);
#pragma unroll
        for (int j = 0; j < 8; ++j) s += xv[j] * (float)w[j];
    }
#pragma unroll
    for (int off = 32; off; off >>= 1) s += __shfl_down(s, off);
    if (lane == 0) {
        float a = addv ? ldin(addv, c, raw32) : 0.f;
        y[c] = s + a;
    }
}

// score[b,n] = v . tanh(sum_2 t2P + sum_4 sprojP + tbias + cov*Wc); grid (PN,PB)
__global__ __launch_bounds__(256) void scores_kernel(
    const bf16* __restrict__ tP, const float* __restrict__ sprojP,
    const float* __restrict__ tbias, const void* __restrict__ cov,
    const void* __restrict__ Wc, const void* __restrict__ v,
    const int* __restrict__ flag, float* __restrict__ sc)
{
    const bool in32 = (flag[0] == 0);
    const int n = blockIdx.x, b = blockIdx.y, tid = threadIdx.x;
    __shared__ float red[4];
    const size_t trow = (size_t)(b * PN + n) * PA;
    const float cv = ldin(cov, b * PN + n, in32);
    float s = 0.f;
#pragma unroll
    for (int i = 0; i < 4; ++i) {
        int a = tid + i * 256;
        float tv = 0.f;
#pragma unroll
        for (int p = 0; p < 2; ++p)
            tv += (float)tP[(size_t)p * ((size_t)PM1 * PA) + trow + a];
        float sp = 0.f;
#pragma unroll
        for (int p = 0; p < 4; ++p)
            sp += sprojP[(size_t)p * (PB * PA) + (size_t)b * PA + a];
        s += ldin(v, a, in32) * tanhf(tv + sp + tbias[a] + cv * ldin(Wc, a, in32));
    }
#pragma unroll
    for (int off = 32; off; off >>= 1) s += __shfl_down(s, off);
    if ((tid & 63) == 0) red[tid >> 6] = s;
    __syncthreads();
    if (tid == 0) sc[b * PN + n] = red[0] + red[1] + red[2] + red[3];
}

// out[b,h] = cbias[h] + sum_n softmax(sc[b,:])_n * gstar[b*PN+n, h]
// grid (PB), block 256, 4 h/thread.  Output dtype per flag.
__global__ __launch_bounds__(256) void context_kernel(
    const float* __restrict__ sc, const bf16* __restrict__ gstar,
    const float* __restrict__ cbias, const int* __restrict__ flag,
    void* __restrict__ out)
{
    const int b = blockIdx.x, tid = threadIdx.x;
    const int h = tid * 4;
    float e[PN];
    float mx = -1e30f;
    for (int n = 0; n < PN; ++n) mx = fmaxf(mx, sc[b * PN + n]);
    float sum = 0.f;
    for (int n = 0; n < PN; ++n) { e[n] = expf(sc[b * PN + n] - mx); sum += e[n]; }
    const float inv = 1.f / sum;
    f32x4 cb = *(const f32x4*)(cbias + h);
    float acc[4] = {cb[0], cb[1], cb[2], cb[3]};
    for (int n = 0; n < PN; ++n) {
        float al = e[n] * inv;
        bf16v4 g = *(const bf16v4*)(gstar + (size_t)(b * PN + n) * PH + h);
#pragma unroll
        for (int j = 0; j < 4; ++j) acc[j] += al * (float)g[j];
    }
    if (flag[0]) {
        bf16v4 o;
#pragma unroll
        for (int j = 0; j < 4; ++j) o[j] = (bf16)acc[j];
        *(bf16v4*)((bf16*)out + (size_t)b * PH + h) = o;
    } else {
        f32x4 o;
#pragma unroll
        for (int j = 0; j < 4; ++j) o[j] = acc[j];
        *(f32x4*)((float*)out + (size_t)b * PH + h) = o;
    }
}

// ---------------------------------------------------------------------------
extern "C" void kernel_launch(void* const* d_in, const int* in_sizes, int n_in,
                              void* d_out, int out_size, void* d_ws, size_t ws_size,
                              hipStream_t stream)
{
    const void* GF  = d_in[0];
    const void* s_t = d_in[1];
    const void* cov = d_in[2];
    const void* Wg  = d_in[3];
    const void* bg  = d_in[4];
    const void* Wgs = d_in[5];
    const void* bgs = d_in[6];
    const void* Wh  = d_in[7];
    const void* Ws  = d_in[8];
    const void* Wc  = d_in[9];
    const void* v   = d_in[10];
    (void)in_sizes; (void)n_in; (void)out_size; (void)ws_size;

    // ---- workspace plan (peak 132 MiB; lifetime-overlap) ----
    // S1 cvt/transpose  S2 biases  S3 WggsT (GEMM+reduce)  S5 g_star GEMM
    // S5b reduce4  S5c t2  S6 sproj  S7 scores  S8 context
    const size_t MB = 1u << 20;
    char* W = (char*)d_ws;
    bf16*  GFb    = (bf16*) (W + 0);               // 49 MiB   [S1-S5]
    bf16*  g_star = (bf16*) (W + 0);               // 12.25MiB [S5b-S8], over dead GFb
    int*   flag   = (int*)  (W + 52 * MB);
    float* tbias  = (float*)(W + 52 * MB + 4096);
    float* cbias  = (float*)(W + 52 * MB + 8192);
    float* sc     = (float*)(W + 52 * MB + 12288); // 25 KB
    bf16*  s_tb   = (bf16*) (W + 52 * MB + 262144);// 0.25 MiB
    bf16*  WsT    = (bf16*) (W + 53 * MB);         // 2 MiB    [S1-S6]
    bf16*  WhT    = (bf16*) (W + 55 * MB);         // 2 MiB    [S1-S5c]
    float* sprojP = (float*)(W + 57 * MB);         // 2 MiB (4 planes) [S6-S7]
    bf16*  WgsT   = (bf16*) (W + 59 * MB);         // 8 MiB    [S1-S3]
    bf16*  WggsT  = (bf16*) (W + 59 * MB);         // 8 MiB    [S3b-S5], over dead WgsT
    bf16*  WggsP  = (bf16*) (W + 67 * MB);         // 32 MiB (4 planes) [S3-S3b]
    bf16*  gP     = (bf16*) (W + 67 * MB);         // 49 MiB (4 planes) [S5-S5b]
    bf16*  t2P    = (bf16*) (W + 67 * MB);         // 24.5 MiB (2 planes) [S5c-S7], over dead gP
    bf16*  Wgb    = (bf16*) (W + 100 * MB);        // 32 MiB   [S1-S3]  peak = 132 MiB

    dim3 blk(256);

    // 0. dtype detect
    detect_kernel<<<dim3(1), blk, 0, stream>>>((const unsigned short*)GF, flag);

    // 1. conversions / transposes of inputs.  Wg IS pre-converted (R3
    //    post-mortem: AADAPT reg-staging GEMM = 141 us; cvt+DMA ~= 80 us).
    cvt_kernel<<<dim3(2048), blk, 0, stream>>>(GF, flag, GFb, (size_t)PM1 * PG);
    cvt_kernel<<<dim3(2048), blk, 0, stream>>>(Wg, flag, Wgb, (size_t)PG * PG);
    cvt_kernel<<<dim3(64), blk, 0, stream>>>(s_t, flag, s_tb, (size_t)PB * PH);
    transpose_kernel<<<dim3(PH / 64, PG / 64), blk, 0, stream>>>(Wgs, flag, WgsT, PG, PH);
    transpose_kernel<<<dim3(PA / 64, PH / 64), blk, 0, stream>>>(Wh, flag, WhT, PH, PA);
    transpose_kernel<<<dim3(PA / 64, PH / 64), blk, 0, stream>>>(Ws, flag, WsT, PH, PA);

    // 2. cbias = bg@Wgs + bgs;  tbias = cbias@Wh
    rowdot_kernel<<<dim3(PH / 4), blk, 0, stream>>>(bg, WgsT, bgs, flag, 1, cbias, PG);
    rowdot_kernel<<<dim3(PA / 4), blk, 0, stream>>>(cbias, WhT, nullptr, flag, 0, tbias, PH);

    // 3. WggsT[H,G] = WgsT @ Wg^T  (= (Wg@Wgs)^T) — direct transposed output:
    //    A = WgsT [H,G], Bt = Wgb [G,G] raw order.  Split-K 4 -> 1024 blocks,
    //    then elementwise reduce4 (no LDS transpose pass needed).
    gemm_kernel<1><<<dim3(PG / 128, PH / 128, 4), blk, 0, stream>>>(
        WgsT, Wgb, nullptr, WggsP, PH, PG, PG, (PG / 64) / 4);
    reduce4_kernel<<<dim3((PH * PG) / 2048), blk, 0, stream>>>(
        WggsP, WggsT, (size_t)PH * PG);

    // 5. g_star planes = GF @ Wggs  (split-K 4 -> 1568 blocks), then reduce
    gemm_kernel<1><<<dim3(PH / 128, PM1 / 128, 4), blk, 0, stream>>>(
        GFb, WggsT, nullptr, gP, PM1, PH, PG, (PG / 64) / 4);
    reduce4_kernel<<<dim3((PM1 * PH) / 2048), blk, 0, stream>>>(
        gP, g_star, (size_t)PM1 * PH);

    // 5c. t2 = g_star @ Wh  (split-K 2 -> 784 blocks, bf16 planes)
    gemm_kernel<1><<<dim3(PA / 128, PM1 / 128, 2), blk, 0, stream>>>(
        g_star, WhT, nullptr, t2P, PM1, PA, PH, (PH / 64) / 2);

    // 6. sproj = s_t @ Ws   (split-K 4, fp32 planes)
    gemm_kernel<0><<<dim3(PA / 128, 1, 4), blk, 0, stream>>>(
        s_tb, WsT, sprojP, nullptr, PB, PA, PH, (PH / 64) / 4);

    // 7. scores (adds tbias so t2 needs no bias)
    scores_kernel<<<dim3(PN, PB), blk, 0, stream>>>(
        t2P, sprojP, tbias, cov, Wc, v, flag, sc);

    // 8. context: softmax + weighted sum of g_star + cbias -> out
    context_kernel<<<dim3(PB), blk, 0, stream>>>(sc, g_star, cbias, flag, d_out);
}